// Round 8
// baseline (448.872 us; speedup 1.0000x reference)
//
#include <hip/hip_runtime.h>

#define NN 100000
#define NE 800000
#define NBUCK 196  // ceil(NN/512)
#define EPB 3125   // NE / 256 edge-blocks
#define BCAP 6144  // max edges per 512-node bucket (mean 4082)

typedef __attribute__((ext_vector_type(8))) short short8;
typedef __attribute__((ext_vector_type(4))) float f32x4;

__device__ __forceinline__ unsigned short f2b(float x) {
  unsigned int u = __float_as_uint(x);
  u = u + 0x7fffu + ((u >> 16) & 1u);
  return (unsigned short)(u >> 16);
}
__device__ __forceinline__ float b2f(unsigned short s) {
  return __uint_as_float(((unsigned int)s) << 16);
}

// ============ edge bucket sort (gather sequential, scatter coalesced) =======

__global__ __launch_bounds__(256) void ehist(const int* __restrict__ dst,
                                             int* __restrict__ hp) {
  __shared__ int lh[NBUCK];
  int tid = threadIdx.x;
  if (tid < NBUCK) lh[tid] = 0;
  __syncthreads();
  int e0 = blockIdx.x * EPB;
  for (int i = tid; i < EPB; i += 256) atomicAdd(&lh[dst[e0 + i] >> 9], 1);
  __syncthreads();
  if (tid < NBUCK) hp[blockIdx.x * NBUCK + tid] = lh[tid];
}

__global__ void escan(int* __restrict__ hp, int* __restrict__ bucket_start) {
  __shared__ int wsum[4];
  int b = threadIdx.x;
  int running = 0;
  if (b < NBUCK) {
    for (int blk = 0; blk < 256; ++blk) {
      int t = hp[blk * NBUCK + b];
      hp[blk * NBUCK + b] = running;
      running += t;
    }
  }
  int lane = b & 63, wv = b >> 6;
  int v = running;
#pragma unroll
  for (int off = 1; off < 64; off <<= 1) {
    int t = __shfl_up(v, off);
    if (lane >= off) v += t;
  }
  if (lane == 63) wsum[wv] = v;
  __syncthreads();
  int wpre = 0;
  for (int j = 0; j < wv; ++j) wpre += wsum[j];
  int excl = v + wpre - running;
  if (b <= NBUCK) bucket_start[b] = excl;
}

// sequential gather of all 5 edge arrays; coalesced record scatter to buckets
__global__ __launch_bounds__(256) void escatter(
    const int* __restrict__ dst, const int* __restrict__ src,
    const float* __restrict__ si, const float* __restrict__ di,
    const float* __restrict__ rv, const int* __restrict__ hp,
    const int* __restrict__ bucket_start, float4* __restrict__ erec_tmp,
    unsigned short* __restrict__ lbkt) {
  __shared__ int cur[NBUCK];
  int tid = threadIdx.x;
  if (tid < NBUCK) cur[tid] = bucket_start[tid] + hp[blockIdx.x * NBUCK + tid];
  __syncthreads();
  int e0 = blockIdx.x * EPB;
  for (int i = tid; i < EPB; i += 256) {
    int e = e0 + i;
    int d = dst[e];
    int pos = atomicAdd(&cur[d >> 9], 1);
    float4 r;
    r.x = __int_as_float(src[e]);
    r.y = si[e];
    r.z = di[e];
    r.w = rv[e];
    erec_tmp[pos] = r;
    lbkt[pos] = (unsigned short)(d & 511);
  }
}

// per bucket: CSR permutation (L2-window scatter) + deg/meta + degree-bin hist
__global__ __launch_bounds__(256) void bucket_csr(
    const unsigned short* __restrict__ lbkt, const int* __restrict__ bstart,
    const float4* __restrict__ erec_tmp, float4* __restrict__ erec,
    int* __restrict__ deg, float4* __restrict__ meta, int* __restrict__ nhp) {
  __shared__ unsigned short lb[BCAP];
  __shared__ int cnt[512];
  __shared__ int excl[512];
  __shared__ int dh[64];
  __shared__ int wsum[4];
  int b = blockIdx.x, tid = threadIdx.x;
  int s0 = bstart[b];
  int size = bstart[b + 1] - s0;
  if (size > BCAP) size = BCAP;
  cnt[2 * tid] = 0;
  cnt[2 * tid + 1] = 0;
  if (tid < 64) dh[tid] = 0;
  __syncthreads();
  for (int p = tid; p < size; p += 256) {
    unsigned short v = lbkt[s0 + p];
    lb[p] = v;
    atomicAdd(&cnt[v], 1);
  }
  __syncthreads();
  int a = cnt[2 * tid], c = cnt[2 * tid + 1];
  int ps = a + c;
  int lane = tid & 63, wv = tid >> 6;
  int v = ps;
#pragma unroll
  for (int off = 1; off < 64; off <<= 1) {
    int t = __shfl_up(v, off);
    if (lane >= off) v += t;
  }
  if (lane == 63) wsum[wv] = v;
  __syncthreads();
  int wpre = 0;
  for (int j = 0; j < wv; ++j) wpre += wsum[j];
  int ex = v + wpre - ps;  // exclusive over node pairs
  excl[2 * tid] = ex;
  excl[2 * tid + 1] = ex + a;
  int n0 = b << 9;
#pragma unroll
  for (int j = 0; j < 2; ++j) {
    int i = 2 * tid + j;
    int n = n0 + i;
    if (n < NN) {
      int d = j ? c : a;
      int rs = s0 + (j ? ex + a : ex);
      deg[n] = d;
      float4 m;
      m.x = __int_as_float(rs);
      m.y = __int_as_float(d);
      m.z = 1.0f / (float)((d > 1) ? d : 1);
      m.w = 0.f;
      meta[n] = m;
      atomicAdd(&dh[(d < 63) ? d : 63], 1);
    }
  }
  cnt[2 * tid] = 0;
  cnt[2 * tid + 1] = 0;
  __syncthreads();
  // single-pass move: sequential read, scatter within 64KB L2 window
  for (int p = tid; p < size; p += 256) {
    int ld = lb[p];
    int pos = excl[ld] + atomicAdd(&cnt[ld], 1);
    erec[s0 + pos] = erec_tmp[s0 + p];
  }
  if (tid < 64) nhp[b * 64 + tid] = dh[tid];
}

// ============ node degree-bucket order ============

__global__ void nscan(int* __restrict__ nhp, int* __restrict__ nbin_start) {
  int b = threadIdx.x;
  int running = 0;
  for (int blk = 0; blk < NBUCK; ++blk) {
    int t = nhp[blk * 64 + b];
    nhp[blk * 64 + b] = running;
    running += t;
  }
  int v = running, s = running;
#pragma unroll
  for (int off = 1; off < 64; off <<= 1) {
    int t = __shfl_up(s, off);
    if (b >= off) s += t;
  }
  nbin_start[b] = s - v;
}

__global__ __launch_bounds__(256) void nscatter(
    const int* __restrict__ deg, const int* __restrict__ nhp,
    const int* __restrict__ nbin_start, int* __restrict__ order) {
  __shared__ int cur[64];
  int tid = threadIdx.x;
  if (tid < 64) cur[tid] = nbin_start[tid] + nhp[blockIdx.x * 64 + tid];
  __syncthreads();
  int n0 = blockIdx.x * 512;
#pragma unroll
  for (int j = 0; j < 2; ++j) {
    int n = n0 + tid + j * 256;
    if (n < NN) {
      int d = deg[n];
      int pos = atomicAdd(&cur[(d < 63) ? d : 63], 1);
      order[pos] = n;
    }
  }
}

// ------- aggregation: quarter-wave per node; 2 edges/iter, deep pipeline ----

__global__ __launch_bounds__(256) void aggregate(
    const unsigned short* __restrict__ H1, const float4* __restrict__ meta,
    const int* __restrict__ order, const float4* __restrict__ erec,
    const float* __restrict__ W1, unsigned short* __restrict__ hNs) {
  __shared__ float wcol[3][64];
  int tid = threadIdx.x;
  if (tid < 192) {
    int f = tid & 63, j = tid >> 6;
    wcol[j][f] = W1[f * 67 + 64 + j];
  }
  __syncthreads();
  int l = tid & 63;
  int fl = l & 15, f0 = fl * 4;
  int qidx = blockIdx.x * 16 + (tid >> 4);
  float wa[4], wb[4], wc[4];
#pragma unroll
  for (int j = 0; j < 4; ++j) {
    wa[j] = wcol[0][f0 + j];
    wb[j] = wcol[1][f0 + j];
    wc[j] = wcol[2][f0 + j];
  }
  if (qidx >= NN) return;
  int n = order[qidx];
  float4 m = meta[n];
  int s0 = __float_as_int(m.x);
  int cnt = __float_as_int(m.y);
  float invd = m.z;
  float acc0[4] = {0.f, 0.f, 0.f, 0.f};
  float acc1[4] = {0.f, 0.f, 0.f, 0.f};
  float4 Z;
  Z.x = Z.y = Z.z = Z.w = 0.f;
  ushort4 HZ = make_ushort4(0, 0, 0, 0);
  // record ring r[0..5] = edges k..k+5; row ring hh[0..3] = rows k..k+3
  float4 r0 = (0 < cnt) ? erec[s0 + 0] : Z;
  float4 r1 = (1 < cnt) ? erec[s0 + 1] : Z;
  float4 r2 = (2 < cnt) ? erec[s0 + 2] : Z;
  float4 r3 = (3 < cnt) ? erec[s0 + 3] : Z;
  float4 r4 = (4 < cnt) ? erec[s0 + 4] : Z;
  float4 r5 = (5 < cnt) ? erec[s0 + 5] : Z;
  ushort4 h0 = (0 < cnt) ? *(const ushort4*)&H1[(size_t)__float_as_int(r0.x) * 64 + f0] : HZ;
  ushort4 h1 = (1 < cnt) ? *(const ushort4*)&H1[(size_t)__float_as_int(r1.x) * 64 + f0] : HZ;
  ushort4 h2 = (2 < cnt) ? *(const ushort4*)&H1[(size_t)__float_as_int(r2.x) * 64 + f0] : HZ;
  ushort4 h3 = (3 < cnt) ? *(const ushort4*)&H1[(size_t)__float_as_int(r3.x) * 64 + f0] : HZ;
  for (int k = 0; k < cnt; k += 2) {
    // prefetch: records k+6,k+7; rows k+4,k+5 (zeroed tails contribute 0)
    float4 r6 = (k + 6 < cnt) ? erec[s0 + k + 6] : Z;
    float4 r7 = (k + 7 < cnt) ? erec[s0 + k + 7] : Z;
    ushort4 h4 = (k + 4 < cnt) ? *(const ushort4*)&H1[(size_t)__float_as_int(r4.x) * 64 + f0] : HZ;
    ushort4 h5 = (k + 5 < cnt) ? *(const ushort4*)&H1[(size_t)__float_as_int(r5.x) * 64 + f0] : HZ;
    float hx0[4] = {b2f(h0.x), b2f(h0.y), b2f(h0.z), b2f(h0.w)};
    float hx1[4] = {b2f(h1.x), b2f(h1.y), b2f(h1.z), b2f(h1.w)};
#pragma unroll
    for (int j = 0; j < 4; ++j) {
      float v0 = hx0[j] + r0.y * wa[j] + r0.z * wb[j] + r0.w * wc[j];
      acc0[j] += (v0 >= 0.f) ? v0 : 0.01f * v0;
      float v1 = hx1[j] + r1.y * wa[j] + r1.z * wb[j] + r1.w * wc[j];
      acc1[j] += (v1 >= 0.f) ? v1 : 0.01f * v1;
    }
    r0 = r2; r1 = r3; r2 = r4; r3 = r5; r4 = r6; r5 = r7;
    h0 = h2; h1 = h3; h2 = h4; h3 = h5;
  }
  ushort4 o = make_ushort4(
      f2b((acc0[0] + acc1[0]) * invd), f2b((acc0[1] + acc1[1]) * invd),
      f2b((acc0[2] + acc1[2]) * invd), f2b((acc0[3] + acc1[3]) * invd));
  *(ushort4*)&hNs[(size_t)n * 64 + f0] = o;
}

// ---------------- fused GEMM helpers ----------------

__device__ __forceinline__ void stageW(const float* W, int ws,
                                       unsigned short* lds, int CO, int K,
                                       int tid) {
  for (int idx = tid; idx < CO * K; idx += 256) {
    int c = idx / K, k = idx - c * K;
    int byte = (c * K + k) * 2;
    byte ^= ((c & 7) << 4);
    *(unsigned short*)((char*)lds + byte) = f2b(W[c * ws + k]);
  }
}
__device__ __forceinline__ short8 ldW(const unsigned short* lds, int K, int c,
                                      int k) {
  int byte = (c * K + k) * 2;
  byte ^= ((c & 7) << 4);
  return *(const short8*)((const char*)lds + byte);
}
__device__ __forceinline__ void stH(unsigned short* ht, int row, int col,
                                    unsigned short v) {
  int byte = row * 128 + col * 2;
  byte ^= ((row & 7) << 4);
  *(unsigned short*)((char*)ht + byte) = v;
}
__device__ __forceinline__ short8 ldH(const unsigned short* ht, int row,
                                      int k) {
  int byte = row * 128 + k * 2;
  byte ^= ((row & 7) << 4);
  return *(const short8*)((const char*)ht + byte);
}

// fused0: h0 = emb[gate]; H1 = h0 @ W1c^T ; write h0, H1
__global__ __launch_bounds__(256) void fused0(
    const int* __restrict__ gate, const float* __restrict__ emb,
    const float* __restrict__ W1, unsigned short* __restrict__ hout,
    unsigned short* __restrict__ H1out) {
  __shared__ unsigned short W1l[64 * 64];
  int tid = threadIdx.x;
  int w = tid >> 6, l = tid & 63, r16 = l & 15, kg = l >> 4;
  int row_base = blockIdx.x * 128 + w * 32;
  // hoist global loads above staging (overlap HBM latency with LDS fill)
  short8 A0[2], A1[2];
#pragma unroll
  for (int rt = 0; rt < 2; ++rt) {
    int arow = row_base + rt * 16 + r16;
    short8 a0 = {0, 0, 0, 0, 0, 0, 0, 0};
    short8 a1 = {0, 0, 0, 0, 0, 0, 0, 0};
    if (arow < NN) {
      int g = gate[arow];
      const float* ep = &emb[g * 64];
      float4 e0 = *(const float4*)&ep[kg * 8];
      float4 e1 = *(const float4*)&ep[kg * 8 + 4];
      float4 e2 = *(const float4*)&ep[32 + kg * 8];
      float4 e3 = *(const float4*)&ep[32 + kg * 8 + 4];
      a0[0] = (short)f2b(e0.x); a0[1] = (short)f2b(e0.y);
      a0[2] = (short)f2b(e0.z); a0[3] = (short)f2b(e0.w);
      a0[4] = (short)f2b(e1.x); a0[5] = (short)f2b(e1.y);
      a0[6] = (short)f2b(e1.z); a0[7] = (short)f2b(e1.w);
      a1[0] = (short)f2b(e2.x); a1[1] = (short)f2b(e2.y);
      a1[2] = (short)f2b(e2.z); a1[3] = (short)f2b(e2.w);
      a1[4] = (short)f2b(e3.x); a1[5] = (short)f2b(e3.y);
      a1[6] = (short)f2b(e3.z); a1[7] = (short)f2b(e3.w);
    }
    A0[rt] = a0;
    A1[rt] = a1;
  }
  stageW(W1, 67, W1l, 64, 64, tid);
  __syncthreads();
  f32x4 acc[2][4];
#pragma unroll
  for (int rt = 0; rt < 2; ++rt)
#pragma unroll
    for (int ct = 0; ct < 4; ++ct) {
      f32x4 z = {0.f, 0.f, 0.f, 0.f};
      acc[rt][ct] = z;
    }
#pragma unroll
  for (int rt = 0; rt < 2; ++rt) {
    int arow = row_base + rt * 16 + r16;
    if (arow < NN) {
      *(short8*)&hout[(size_t)arow * 64 + kg * 8] = A0[rt];
      *(short8*)&hout[(size_t)arow * 64 + 32 + kg * 8] = A1[rt];
    }
#pragma unroll
    for (int ct = 0; ct < 4; ++ct) {
      int c = ct * 16 + r16;
      acc[rt][ct] = __builtin_amdgcn_mfma_f32_16x16x32_bf16(
          A0[rt], ldW(W1l, 64, c, kg * 8), acc[rt][ct], 0, 0, 0);
      acc[rt][ct] = __builtin_amdgcn_mfma_f32_16x16x32_bf16(
          A1[rt], ldW(W1l, 64, c, 32 + kg * 8), acc[rt][ct], 0, 0, 0);
    }
  }
#pragma unroll
  for (int rt = 0; rt < 2; ++rt)
#pragma unroll
    for (int ct = 0; ct < 4; ++ct) {
      int col = ct * 16 + r16;
#pragma unroll
      for (int i = 0; i < 4; ++i) {
        int row = row_base + rt * 16 + kg * 4 + i;
        if (row < NN) H1out[(size_t)row * 64 + col] = f2b(acc[rt][ct][i]);
      }
    }
}

// fused_mid: hnew = relu(h@W2a + hNs@W2b + b2); H1 = hnew@W1n_c^T
__global__ __launch_bounds__(256) void fused_mid(
    const unsigned short* h, const unsigned short* __restrict__ hNs,
    const float* __restrict__ W2, const float* __restrict__ b2,
    const float* __restrict__ W1n, unsigned short* hout,
    unsigned short* __restrict__ H1out) {
  __shared__ unsigned short W2l[64 * 128];
  __shared__ unsigned short W1l[64 * 64];
  __shared__ unsigned short ht[128 * 64];
  int tid = threadIdx.x;
  int w = tid >> 6, l = tid & 63, r16 = l & 15, kg = l >> 4;
  int row_base = blockIdx.x * 128 + w * 32;
  // hoist h/hNs loads above W staging
  short8 A0[2], A1[2], C0[2], C1[2];
#pragma unroll
  for (int rt = 0; rt < 2; ++rt) {
    int arow = row_base + rt * 16 + r16;
    short8 z = {0, 0, 0, 0, 0, 0, 0, 0};
    A0[rt] = z; A1[rt] = z; C0[rt] = z; C1[rt] = z;
    if (arow < NN) {
      A0[rt] = *(const short8*)&h[(size_t)arow * 64 + kg * 8];
      A1[rt] = *(const short8*)&h[(size_t)arow * 64 + 32 + kg * 8];
      C0[rt] = *(const short8*)&hNs[(size_t)arow * 64 + kg * 8];
      C1[rt] = *(const short8*)&hNs[(size_t)arow * 64 + 32 + kg * 8];
    }
  }
  stageW(W2, 128, W2l, 64, 128, tid);
  stageW(W1n, 67, W1l, 64, 64, tid);
  __syncthreads();
  f32x4 acc[2][4];
#pragma unroll
  for (int rt = 0; rt < 2; ++rt)
#pragma unroll
    for (int ct = 0; ct < 4; ++ct) {
      f32x4 z = {0.f, 0.f, 0.f, 0.f};
      acc[rt][ct] = z;
    }
#pragma unroll
  for (int rt = 0; rt < 2; ++rt) {
#pragma unroll
    for (int ct = 0; ct < 4; ++ct) {
      int c = ct * 16 + r16;
      acc[rt][ct] = __builtin_amdgcn_mfma_f32_16x16x32_bf16(
          A0[rt], ldW(W2l, 128, c, kg * 8), acc[rt][ct], 0, 0, 0);
      acc[rt][ct] = __builtin_amdgcn_mfma_f32_16x16x32_bf16(
          A1[rt], ldW(W2l, 128, c, 32 + kg * 8), acc[rt][ct], 0, 0, 0);
      acc[rt][ct] = __builtin_amdgcn_mfma_f32_16x16x32_bf16(
          C0[rt], ldW(W2l, 128, c, 64 + kg * 8), acc[rt][ct], 0, 0, 0);
      acc[rt][ct] = __builtin_amdgcn_mfma_f32_16x16x32_bf16(
          C1[rt], ldW(W2l, 128, c, 96 + kg * 8), acc[rt][ct], 0, 0, 0);
    }
  }
#pragma unroll
  for (int rt = 0; rt < 2; ++rt)
#pragma unroll
    for (int ct = 0; ct < 4; ++ct) {
      int col = ct * 16 + r16;
      float bv = b2[col];
#pragma unroll
      for (int i = 0; i < 4; ++i) {
        int lrow = w * 32 + rt * 16 + kg * 4 + i;
        float v = acc[rt][ct][i] + bv;
        v = fmaxf(v, 0.f);
        stH(ht, lrow, col, f2b(v));
      }
    }
  __syncthreads();
  f32x4 acc2[2][4];
#pragma unroll
  for (int rt = 0; rt < 2; ++rt)
#pragma unroll
    for (int ct = 0; ct < 4; ++ct) {
      f32x4 z = {0.f, 0.f, 0.f, 0.f};
      acc2[rt][ct] = z;
    }
#pragma unroll
  for (int rt = 0; rt < 2; ++rt) {
    int lrow = w * 32 + rt * 16 + r16;
    int arow = row_base + rt * 16 + r16;
    short8 a0 = ldH(ht, lrow, kg * 8);
    short8 a1 = ldH(ht, lrow, 32 + kg * 8);
    if (arow < NN) {
      *(short8*)&hout[(size_t)arow * 64 + kg * 8] = a0;
      *(short8*)&hout[(size_t)arow * 64 + 32 + kg * 8] = a1;
    }
#pragma unroll
    for (int ct = 0; ct < 4; ++ct) {
      int c = ct * 16 + r16;
      acc2[rt][ct] = __builtin_amdgcn_mfma_f32_16x16x32_bf16(
          a0, ldW(W1l, 64, c, kg * 8), acc2[rt][ct], 0, 0, 0);
      acc2[rt][ct] = __builtin_amdgcn_mfma_f32_16x16x32_bf16(
          a1, ldW(W1l, 64, c, 32 + kg * 8), acc2[rt][ct], 0, 0, 0);
    }
  }
#pragma unroll
  for (int rt = 0; rt < 2; ++rt)
#pragma unroll
    for (int ct = 0; ct < 4; ++ct) {
      int col = ct * 16 + r16;
#pragma unroll
      for (int i = 0; i < 4; ++i) {
        int row = row_base + rt * 16 + kg * 4 + i;
        if (row < NN) H1out[(size_t)row * 64 + col] = f2b(acc2[rt][ct][i]);
      }
    }
}

// fused_final: h5 = relu(h@W2a+hNs@W2b+b2); t = relu(h5@Wl1^T+bl1);
//              out = t@Wl2^T + bl2   (f32)
__global__ __launch_bounds__(256) void fused_final(
    const unsigned short* __restrict__ h, const unsigned short* __restrict__ hNs,
    const float* __restrict__ W2, const float* __restrict__ b2,
    const float* __restrict__ Wl1, const float* __restrict__ bl1,
    const float* __restrict__ Wl2, const float* __restrict__ bl2,
    float* __restrict__ out) {
  __shared__ unsigned short W2l[64 * 128];
  __shared__ unsigned short Al[64 * 64];
  __shared__ unsigned short Bl[32 * 64];
  __shared__ unsigned short ht[128 * 64];
  int tid = threadIdx.x;
  int w = tid >> 6, l = tid & 63, r16 = l & 15, kg = l >> 4;
  int row_base = blockIdx.x * 128 + w * 32;
  short8 A0[2], A1[2], C0[2], C1[2];
#pragma unroll
  for (int rt = 0; rt < 2; ++rt) {
    int arow = row_base + rt * 16 + r16;
    short8 z = {0, 0, 0, 0, 0, 0, 0, 0};
    A0[rt] = z; A1[rt] = z; C0[rt] = z; C1[rt] = z;
    if (arow < NN) {
      A0[rt] = *(const short8*)&h[(size_t)arow * 64 + kg * 8];
      A1[rt] = *(const short8*)&h[(size_t)arow * 64 + 32 + kg * 8];
      C0[rt] = *(const short8*)&hNs[(size_t)arow * 64 + kg * 8];
      C1[rt] = *(const short8*)&hNs[(size_t)arow * 64 + 32 + kg * 8];
    }
  }
  stageW(W2, 128, W2l, 64, 128, tid);
  stageW(Wl1, 64, Al, 64, 64, tid);
  stageW(Wl2, 64, Bl, 32, 64, tid);
  __syncthreads();
  f32x4 acc[2][4];
#pragma unroll
  for (int rt = 0; rt < 2; ++rt)
#pragma unroll
    for (int ct = 0; ct < 4; ++ct) {
      f32x4 z = {0.f, 0.f, 0.f, 0.f};
      acc[rt][ct] = z;
    }
#pragma unroll
  for (int rt = 0; rt < 2; ++rt) {
#pragma unroll
    for (int ct = 0; ct < 4; ++ct) {
      int c = ct * 16 + r16;
      acc[rt][ct] = __builtin_amdgcn_mfma_f32_16x16x32_bf16(
          A0[rt], ldW(W2l, 128, c, kg * 8), acc[rt][ct], 0, 0, 0);
      acc[rt][ct] = __builtin_amdgcn_mfma_f32_16x16x32_bf16(
          A1[rt], ldW(W2l, 128, c, 32 + kg * 8), acc[rt][ct], 0, 0, 0);
      acc[rt][ct] = __builtin_amdgcn_mfma_f32_16x16x32_bf16(
          C0[rt], ldW(W2l, 128, c, 64 + kg * 8), acc[rt][ct], 0, 0, 0);
      acc[rt][ct] = __builtin_amdgcn_mfma_f32_16x16x32_bf16(
          C1[rt], ldW(W2l, 128, c, 96 + kg * 8), acc[rt][ct], 0, 0, 0);
    }
  }
#pragma unroll
  for (int rt = 0; rt < 2; ++rt)
#pragma unroll
    for (int ct = 0; ct < 4; ++ct) {
      int col = ct * 16 + r16;
      float bv = b2[col];
#pragma unroll
      for (int i = 0; i < 4; ++i) {
        int lrow = w * 32 + rt * 16 + kg * 4 + i;
        float v = acc[rt][ct][i] + bv;
        v = fmaxf(v, 0.f);
        stH(ht, lrow, col, f2b(v));
      }
    }
  __syncthreads();
  f32x4 acc2[2][4];
#pragma unroll
  for (int rt = 0; rt < 2; ++rt)
#pragma unroll
    for (int ct = 0; ct < 4; ++ct) {
      f32x4 z = {0.f, 0.f, 0.f, 0.f};
      acc2[rt][ct] = z;
    }
#pragma unroll
  for (int rt = 0; rt < 2; ++rt) {
    int lrow = w * 32 + rt * 16 + r16;
    short8 a0 = ldH(ht, lrow, kg * 8);
    short8 a1 = ldH(ht, lrow, 32 + kg * 8);
#pragma unroll
    for (int ct = 0; ct < 4; ++ct) {
      int c = ct * 16 + r16;
      acc2[rt][ct] = __builtin_amdgcn_mfma_f32_16x16x32_bf16(
          a0, ldW(Al, 64, c, kg * 8), acc2[rt][ct], 0, 0, 0);
      acc2[rt][ct] = __builtin_amdgcn_mfma_f32_16x16x32_bf16(
          a1, ldW(Al, 64, c, 32 + kg * 8), acc2[rt][ct], 0, 0, 0);
    }
  }
  __syncthreads();
#pragma unroll
  for (int rt = 0; rt < 2; ++rt)
#pragma unroll
    for (int ct = 0; ct < 4; ++ct) {
      int col = ct * 16 + r16;
      float bv = bl1[col];
#pragma unroll
      for (int i = 0; i < 4; ++i) {
        int lrow = w * 32 + rt * 16 + kg * 4 + i;
        float v = acc2[rt][ct][i] + bv;
        v = fmaxf(v, 0.f);
        stH(ht, lrow, col, f2b(v));
      }
    }
  __syncthreads();
  f32x4 acc3[2][2];
#pragma unroll
  for (int rt = 0; rt < 2; ++rt)
#pragma unroll
    for (int ct = 0; ct < 2; ++ct) {
      f32x4 z = {0.f, 0.f, 0.f, 0.f};
      acc3[rt][ct] = z;
    }
#pragma unroll
  for (int rt = 0; rt < 2; ++rt) {
    int lrow = w * 32 + rt * 16 + r16;
    short8 a0 = ldH(ht, lrow, kg * 8);
    short8 a1 = ldH(ht, lrow, 32 + kg * 8);
#pragma unroll
    for (int ct = 0; ct < 2; ++ct) {
      int c = ct * 16 + r16;
      acc3[rt][ct] = __builtin_amdgcn_mfma_f32_16x16x32_bf16(
          a0, ldW(Bl, 64, c, kg * 8), acc3[rt][ct], 0, 0, 0);
      acc3[rt][ct] = __builtin_amdgcn_mfma_f32_16x16x32_bf16(
          a1, ldW(Bl, 64, c, 32 + kg * 8), acc3[rt][ct], 0, 0, 0);
    }
  }
#pragma unroll
  for (int rt = 0; rt < 2; ++rt)
#pragma unroll
    for (int ct = 0; ct < 2; ++ct) {
      int col = ct * 16 + r16;
      float bv = bl2[col];
#pragma unroll
      for (int i = 0; i < 4; ++i) {
        int row = row_base + rt * 16 + kg * 4 + i;
        if (row < NN) out[(size_t)row * 32 + col] = acc3[rt][ct][i] + bv;
      }
    }
}

// ---------------- launcher ----------------

extern "C" void kernel_launch(void* const* d_in, const int* in_sizes, int n_in,
                              void* d_out, int out_size, void* d_ws, size_t ws_size,
                              hipStream_t stream) {
  const int* gate = (const int*)d_in[0];
  const int* src = (const int*)d_in[1];
  const int* dst = (const int*)d_in[2];
  const float* src_idx = (const float*)d_in[3];
  const float* dst_idx = (const float*)d_in[4];
  const float* rev = (const float*)d_in[5];
  const float* emb = (const float*)d_in[6];
  const float* W1 = (const float*)d_in[7];
  const float* W2 = (const float*)d_in[8];
  const float* b2 = (const float*)d_in[9];
  const float* Wl1 = (const float*)d_in[10];
  const float* bl1 = (const float*)d_in[11];
  const float* Wl2 = (const float*)d_in[12];
  const float* bl2 = (const float*)d_in[13];
  float* out = (float*)d_out;

  char* ws = (char*)d_ws;
  unsigned short* h = (unsigned short*)(ws + 0);             // 12.8 MB
  unsigned short* lbkt = (unsigned short*)(ws + 0);          // aliases h (build)
  unsigned short* H1 = (unsigned short*)(ws + 12800000);     // 12.8 MB
  unsigned short* hNs = (unsigned short*)(ws + 25600000);    // 12.8 MB
  float4* erec_tmp = (float4*)(ws + 25600000);               // aliases hNs (build)
  float4* erec = (float4*)(ws + 38400000);                   // 12.8 MB
  float4* meta = (float4*)(ws + 51200000);                   // 1.6 MB
  int* order = (int*)(ws + 52800000);                        // 0.4 MB
  int* deg = (int*)(ws + 53200000);                          // 0.4 MB
  int* hist_part = (int*)(ws + 53600000);                    // 256*196*4
  int* bucket_start = (int*)(ws + 53810000);                 // 197 ints
  int* nhp = (int*)(ws + 53820000);                          // 196*64*4
  int* nbin_start = (int*)(ws + 53880000);                   // 64 ints

  ehist<<<256, 256, 0, stream>>>(dst, hist_part);
  escan<<<1, 256, 0, stream>>>(hist_part, bucket_start);
  escatter<<<256, 256, 0, stream>>>(dst, src, src_idx, dst_idx, rev, hist_part,
                                    bucket_start, erec_tmp, lbkt);
  bucket_csr<<<NBUCK, 256, 0, stream>>>(lbkt, bucket_start, erec_tmp, erec,
                                        deg, meta, nhp);
  nscan<<<1, 64, 0, stream>>>(nhp, nbin_start);
  nscatter<<<NBUCK, 256, 0, stream>>>(deg, nhp, nbin_start, order);

  fused0<<<782, 256, 0, stream>>>(gate, emb, W1, h, H1);
  for (int i = 0; i < 5; ++i) {
    aggregate<<<6250, 256, 0, stream>>>(H1, meta, order,
                                        erec, W1 + i * 64 * 67, hNs);
    if (i < 4)
      fused_mid<<<782, 256, 0, stream>>>(h, hNs, W2 + i * 64 * 128, b2 + i * 64,
                                         W1 + (i + 1) * 64 * 67, h, H1);
  }
  fused_final<<<782, 256, 0, stream>>>(h, hNs, W2 + 4 * 64 * 128, b2 + 4 * 64,
                                       Wl1, bl1, Wl2, bl2, out);
}

// Round 9
// 377.080 us; speedup vs baseline: 1.1904x; 1.1904x over previous
//
#include <hip/hip_runtime.h>

#define NN 100000
#define NE 800000
#define NBUCK 196  // ceil(NN/512)
#define EPB 3125   // NE / 256 edge-blocks
#define BCAP 6144  // max edges per 512-node bucket (mean 4082)

typedef __attribute__((ext_vector_type(8))) short short8;
typedef __attribute__((ext_vector_type(4))) float f32x4;

__device__ __forceinline__ unsigned short f2b(float x) {
  unsigned int u = __float_as_uint(x);
  u = u + 0x7fffu + ((u >> 16) & 1u);
  return (unsigned short)(u >> 16);
}
__device__ __forceinline__ float b2f(unsigned short s) {
  return __uint_as_float(((unsigned int)s) << 16);
}

// ============ edge bucket sort (gather sequential, scatter coalesced) =======

__global__ __launch_bounds__(256) void ehist(const int* __restrict__ dst,
                                             int* __restrict__ hp) {
  __shared__ int lh[NBUCK];
  int tid = threadIdx.x;
  if (tid < NBUCK) lh[tid] = 0;
  __syncthreads();
  int e0 = blockIdx.x * EPB;
  for (int i = tid; i < EPB; i += 256) atomicAdd(&lh[dst[e0 + i] >> 9], 1);
  __syncthreads();
  if (tid < NBUCK) hp[blockIdx.x * NBUCK + tid] = lh[tid];
}

__global__ void escan(int* __restrict__ hp, int* __restrict__ bucket_start) {
  __shared__ int wsum[4];
  int b = threadIdx.x;
  int running = 0;
  if (b < NBUCK) {
    for (int blk = 0; blk < 256; ++blk) {
      int t = hp[blk * NBUCK + b];
      hp[blk * NBUCK + b] = running;
      running += t;
    }
  }
  int lane = b & 63, wv = b >> 6;
  int v = running;
#pragma unroll
  for (int off = 1; off < 64; off <<= 1) {
    int t = __shfl_up(v, off);
    if (lane >= off) v += t;
  }
  if (lane == 63) wsum[wv] = v;
  __syncthreads();
  int wpre = 0;
  for (int j = 0; j < wv; ++j) wpre += wsum[j];
  int excl = v + wpre - running;
  if (b <= NBUCK) bucket_start[b] = excl;
}

// sequential gather of all 5 edge arrays; coalesced record scatter to buckets
__global__ __launch_bounds__(256) void escatter(
    const int* __restrict__ dst, const int* __restrict__ src,
    const float* __restrict__ si, const float* __restrict__ di,
    const float* __restrict__ rv, const int* __restrict__ hp,
    const int* __restrict__ bucket_start, float4* __restrict__ erec_tmp,
    unsigned short* __restrict__ lbkt) {
  __shared__ int cur[NBUCK];
  int tid = threadIdx.x;
  if (tid < NBUCK) cur[tid] = bucket_start[tid] + hp[blockIdx.x * NBUCK + tid];
  __syncthreads();
  int e0 = blockIdx.x * EPB;
  for (int i = tid; i < EPB; i += 256) {
    int e = e0 + i;
    int d = dst[e];
    int pos = atomicAdd(&cur[d >> 9], 1);
    float4 r;
    r.x = __int_as_float(src[e]);
    r.y = si[e];
    r.z = di[e];
    r.w = rv[e];
    erec_tmp[pos] = r;
    lbkt[pos] = (unsigned short)(d & 511);
  }
}

// per bucket: CSR permutation (L2-window scatter) + deg/meta + degree-bin hist
__global__ __launch_bounds__(256) void bucket_csr(
    const unsigned short* __restrict__ lbkt, const int* __restrict__ bstart,
    const float4* __restrict__ erec_tmp, float4* __restrict__ erec,
    int* __restrict__ deg, float4* __restrict__ meta, int* __restrict__ nhp) {
  __shared__ unsigned short lb[BCAP];
  __shared__ int cnt[512];
  __shared__ int excl[512];
  __shared__ int dh[64];
  __shared__ int wsum[4];
  int b = blockIdx.x, tid = threadIdx.x;
  int s0 = bstart[b];
  int size = bstart[b + 1] - s0;
  if (size > BCAP) size = BCAP;
  cnt[2 * tid] = 0;
  cnt[2 * tid + 1] = 0;
  if (tid < 64) dh[tid] = 0;
  __syncthreads();
  for (int p = tid; p < size; p += 256) {
    unsigned short v = lbkt[s0 + p];
    lb[p] = v;
    atomicAdd(&cnt[v], 1);
  }
  __syncthreads();
  int a = cnt[2 * tid], c = cnt[2 * tid + 1];
  int ps = a + c;
  int lane = tid & 63, wv = tid >> 6;
  int v = ps;
#pragma unroll
  for (int off = 1; off < 64; off <<= 1) {
    int t = __shfl_up(v, off);
    if (lane >= off) v += t;
  }
  if (lane == 63) wsum[wv] = v;
  __syncthreads();
  int wpre = 0;
  for (int j = 0; j < wv; ++j) wpre += wsum[j];
  int ex = v + wpre - ps;  // exclusive over node pairs
  excl[2 * tid] = ex;
  excl[2 * tid + 1] = ex + a;
  int n0 = b << 9;
#pragma unroll
  for (int j = 0; j < 2; ++j) {
    int i = 2 * tid + j;
    int n = n0 + i;
    if (n < NN) {
      int d = j ? c : a;
      int rs = s0 + (j ? ex + a : ex);
      deg[n] = d;
      float4 m;
      m.x = __int_as_float(rs);
      m.y = __int_as_float(d);
      m.z = 1.0f / (float)((d > 1) ? d : 1);
      m.w = 0.f;
      meta[n] = m;
      atomicAdd(&dh[(d < 63) ? d : 63], 1);
    }
  }
  cnt[2 * tid] = 0;
  cnt[2 * tid + 1] = 0;
  __syncthreads();
  // single-pass move: sequential read, scatter within 64KB L2 window
  for (int p = tid; p < size; p += 256) {
    int ld = lb[p];
    int pos = excl[ld] + atomicAdd(&cnt[ld], 1);
    erec[s0 + pos] = erec_tmp[s0 + p];
  }
  if (tid < 64) nhp[b * 64 + tid] = dh[tid];
}

// ============ node degree-bucket order ============

__global__ void nscan(int* __restrict__ nhp, int* __restrict__ nbin_start) {
  int b = threadIdx.x;
  int running = 0;
  for (int blk = 0; blk < NBUCK; ++blk) {
    int t = nhp[blk * 64 + b];
    nhp[blk * 64 + b] = running;
    running += t;
  }
  int v = running, s = running;
#pragma unroll
  for (int off = 1; off < 64; off <<= 1) {
    int t = __shfl_up(s, off);
    if (b >= off) s += t;
  }
  nbin_start[b] = s - v;
}

__global__ __launch_bounds__(256) void nscatter(
    const int* __restrict__ deg, const int* __restrict__ nhp,
    const int* __restrict__ nbin_start, int* __restrict__ order) {
  __shared__ int cur[64];
  int tid = threadIdx.x;
  if (tid < 64) cur[tid] = nbin_start[tid] + nhp[blockIdx.x * 64 + tid];
  __syncthreads();
  int n0 = blockIdx.x * 512;
#pragma unroll
  for (int j = 0; j < 2; ++j) {
    int n = n0 + tid + j * 256;
    if (n < NN) {
      int d = deg[n];
      int pos = atomicAdd(&cur[(d < 63) ? d : 63], 1);
      order[pos] = n;
    }
  }
}

// ------- aggregation: quarter-wave per node; 3-deep rec / 2-deep row pipe ---

__global__ __launch_bounds__(256) void aggregate(
    const unsigned short* __restrict__ H1, const float4* __restrict__ meta,
    const int* __restrict__ order, const float4* __restrict__ erec,
    const float* __restrict__ W1, unsigned short* __restrict__ hNs) {
  __shared__ float wcol[3][64];
  int tid = threadIdx.x;
  if (tid < 192) {
    int f = tid & 63, j = tid >> 6;
    wcol[j][f] = W1[f * 67 + 64 + j];
  }
  __syncthreads();
  int l = tid & 63;
  int fl = l & 15, f0 = fl * 4;
  int qidx = blockIdx.x * 16 + (tid >> 4);
  float wa[4], wb[4], wc[4];
#pragma unroll
  for (int j = 0; j < 4; ++j) {
    wa[j] = wcol[0][f0 + j];
    wb[j] = wcol[1][f0 + j];
    wc[j] = wcol[2][f0 + j];
  }
  if (qidx >= NN) return;
  int n = order[qidx];
  float4 m = meta[n];
  int s0 = __float_as_int(m.x);
  int cnt = __float_as_int(m.y);
  float invd = m.z;
  float acc[4] = {0.f, 0.f, 0.f, 0.f};
  float4 r0, r1, r2;
  r0.x = r0.y = r0.z = r0.w = 0.f;
  r1 = r0;
  r2 = r0;
  ushort4 h0 = make_ushort4(0, 0, 0, 0), h1 = h0;
  if (cnt > 0) {
    r0 = erec[s0];
    h0 = *(const ushort4*)&H1[(size_t)__float_as_int(r0.x) * 64 + f0];
  }
  if (cnt > 1) {
    r1 = erec[s0 + 1];
    h1 = *(const ushort4*)&H1[(size_t)__float_as_int(r1.x) * 64 + f0];
  }
  if (cnt > 2) r2 = erec[s0 + 2];
  for (int k = 0; k < cnt; ++k) {
    float4 r3;
    r3.x = r3.y = r3.z = r3.w = 0.f;
    if (k + 3 < cnt) r3 = erec[s0 + k + 3];
    ushort4 h2 = make_ushort4(0, 0, 0, 0);
    if (k + 2 < cnt)
      h2 = *(const ushort4*)&H1[(size_t)__float_as_int(r2.x) * 64 + f0];
    float hx[4] = {b2f(h0.x), b2f(h0.y), b2f(h0.z), b2f(h0.w)};
#pragma unroll
    for (int j = 0; j < 4; ++j) {
      float vv = hx[j] + r0.y * wa[j] + r0.z * wb[j] + r0.w * wc[j];
      acc[j] += (vv >= 0.f) ? vv : 0.01f * vv;
    }
    r0 = r1;
    r1 = r2;
    r2 = r3;
    h0 = h1;
    h1 = h2;
  }
  ushort4 o = make_ushort4(f2b(acc[0] * invd), f2b(acc[1] * invd),
                           f2b(acc[2] * invd), f2b(acc[3] * invd));
  *(ushort4*)&hNs[(size_t)n * 64 + f0] = o;
}

// ---------------- fused GEMM helpers ----------------

__device__ __forceinline__ void stageW(const float* W, int ws,
                                       unsigned short* lds, int CO, int K,
                                       int tid, int nt) {
  for (int idx = tid; idx < CO * K; idx += nt) {
    int c = idx / K, k = idx - c * K;
    int byte = (c * K + k) * 2;
    byte ^= ((c & 7) << 4);
    *(unsigned short*)((char*)lds + byte) = f2b(W[c * ws + k]);
  }
}
__device__ __forceinline__ short8 ldW(const unsigned short* lds, int K, int c,
                                      int k) {
  int byte = (c * K + k) * 2;
  byte ^= ((c & 7) << 4);
  return *(const short8*)((const char*)lds + byte);
}
__device__ __forceinline__ void stH(unsigned short* ht, int row, int col,
                                    unsigned short v) {
  int byte = row * 128 + col * 2;
  byte ^= ((row & 7) << 4);
  *(unsigned short*)((char*)ht + byte) = v;
}
__device__ __forceinline__ short8 ldH(const unsigned short* ht, int row,
                                      int k) {
  int byte = row * 128 + k * 2;
  byte ^= ((row & 7) << 4);
  return *(const short8*)((const char*)ht + byte);
}

// fused0: h0 = emb[gate]; H1 = h0 @ W1c^T ; write h0, H1  (256 thr, 128 rows)
__global__ __launch_bounds__(256) void fused0(
    const int* __restrict__ gate, const float* __restrict__ emb,
    const float* __restrict__ W1, unsigned short* __restrict__ hout,
    unsigned short* __restrict__ H1out) {
  __shared__ unsigned short W1l[64 * 64];
  int tid = threadIdx.x;
  stageW(W1, 67, W1l, 64, 64, tid, 256);
  __syncthreads();
  int w = tid >> 6, l = tid & 63, r16 = l & 15, kg = l >> 4;
  int row_base = blockIdx.x * 128 + w * 32;
  f32x4 acc[2][4];
#pragma unroll
  for (int rt = 0; rt < 2; ++rt)
#pragma unroll
    for (int ct = 0; ct < 4; ++ct) {
      f32x4 z = {0.f, 0.f, 0.f, 0.f};
      acc[rt][ct] = z;
    }
#pragma unroll
  for (int rt = 0; rt < 2; ++rt) {
    int arow = row_base + rt * 16 + r16;
    short8 a0 = {0, 0, 0, 0, 0, 0, 0, 0};
    short8 a1 = {0, 0, 0, 0, 0, 0, 0, 0};
    if (arow < NN) {
      int g = gate[arow];
      const float* ep = &emb[g * 64];
      float4 e0 = *(const float4*)&ep[kg * 8];
      float4 e1 = *(const float4*)&ep[kg * 8 + 4];
      float4 e2 = *(const float4*)&ep[32 + kg * 8];
      float4 e3 = *(const float4*)&ep[32 + kg * 8 + 4];
      a0[0] = (short)f2b(e0.x); a0[1] = (short)f2b(e0.y);
      a0[2] = (short)f2b(e0.z); a0[3] = (short)f2b(e0.w);
      a0[4] = (short)f2b(e1.x); a0[5] = (short)f2b(e1.y);
      a0[6] = (short)f2b(e1.z); a0[7] = (short)f2b(e1.w);
      a1[0] = (short)f2b(e2.x); a1[1] = (short)f2b(e2.y);
      a1[2] = (short)f2b(e2.z); a1[3] = (short)f2b(e2.w);
      a1[4] = (short)f2b(e3.x); a1[5] = (short)f2b(e3.y);
      a1[6] = (short)f2b(e3.z); a1[7] = (short)f2b(e3.w);
      *(short8*)&hout[(size_t)arow * 64 + kg * 8] = a0;
      *(short8*)&hout[(size_t)arow * 64 + 32 + kg * 8] = a1;
    }
#pragma unroll
    for (int ct = 0; ct < 4; ++ct) {
      int c = ct * 16 + r16;
      acc[rt][ct] = __builtin_amdgcn_mfma_f32_16x16x32_bf16(
          a0, ldW(W1l, 64, c, kg * 8), acc[rt][ct], 0, 0, 0);
      acc[rt][ct] = __builtin_amdgcn_mfma_f32_16x16x32_bf16(
          a1, ldW(W1l, 64, c, 32 + kg * 8), acc[rt][ct], 0, 0, 0);
    }
  }
#pragma unroll
  for (int rt = 0; rt < 2; ++rt)
#pragma unroll
    for (int ct = 0; ct < 4; ++ct) {
      int col = ct * 16 + r16;
#pragma unroll
      for (int i = 0; i < 4; ++i) {
        int row = row_base + rt * 16 + kg * 4 + i;
        if (row < NN) H1out[(size_t)row * 64 + col] = f2b(acc[rt][ct][i]);
      }
    }
}

// fused_mid: hnew = relu(h@W2a + hNs@W2b + b2); H1 = hnew@W1n_c^T
// 512 threads / 8 waves; each wave owns 16 rows of the 128-row tile.
__global__ __launch_bounds__(512) void fused_mid(
    const unsigned short* h, const unsigned short* __restrict__ hNs,
    const float* __restrict__ W2, const float* __restrict__ b2,
    const float* __restrict__ W1n, unsigned short* hout,
    unsigned short* __restrict__ H1out) {
  __shared__ unsigned short W2l[64 * 128];
  __shared__ unsigned short W1l[64 * 64];
  __shared__ unsigned short ht[128 * 64];
  int tid = threadIdx.x;
  stageW(W2, 128, W2l, 64, 128, tid, 512);
  stageW(W1n, 67, W1l, 64, 64, tid, 512);
  __syncthreads();
  int w = tid >> 6, l = tid & 63, r16 = l & 15, kg = l >> 4;
  int row_base = blockIdx.x * 128 + w * 16;
  int arow = row_base + r16;
  short8 z8 = {0, 0, 0, 0, 0, 0, 0, 0};
  short8 a0 = z8, a1 = z8, c0 = z8, c1 = z8;
  if (arow < NN) {
    a0 = *(const short8*)&h[(size_t)arow * 64 + kg * 8];
    a1 = *(const short8*)&h[(size_t)arow * 64 + 32 + kg * 8];
    c0 = *(const short8*)&hNs[(size_t)arow * 64 + kg * 8];
    c1 = *(const short8*)&hNs[(size_t)arow * 64 + 32 + kg * 8];
  }
  f32x4 acc[4];
#pragma unroll
  for (int ct = 0; ct < 4; ++ct) {
    f32x4 z = {0.f, 0.f, 0.f, 0.f};
    acc[ct] = z;
  }
#pragma unroll
  for (int ct = 0; ct < 4; ++ct) {
    int c = ct * 16 + r16;
    acc[ct] = __builtin_amdgcn_mfma_f32_16x16x32_bf16(
        a0, ldW(W2l, 128, c, kg * 8), acc[ct], 0, 0, 0);
    acc[ct] = __builtin_amdgcn_mfma_f32_16x16x32_bf16(
        a1, ldW(W2l, 128, c, 32 + kg * 8), acc[ct], 0, 0, 0);
    acc[ct] = __builtin_amdgcn_mfma_f32_16x16x32_bf16(
        c0, ldW(W2l, 128, c, 64 + kg * 8), acc[ct], 0, 0, 0);
    acc[ct] = __builtin_amdgcn_mfma_f32_16x16x32_bf16(
        c1, ldW(W2l, 128, c, 96 + kg * 8), acc[ct], 0, 0, 0);
  }
#pragma unroll
  for (int ct = 0; ct < 4; ++ct) {
    int col = ct * 16 + r16;
    float bv = b2[col];
#pragma unroll
    for (int i = 0; i < 4; ++i) {
      int lrow = w * 16 + kg * 4 + i;
      float v = acc[ct][i] + bv;
      v = fmaxf(v, 0.f);
      stH(ht, lrow, col, f2b(v));
    }
  }
  __syncthreads();
  f32x4 acc2[4];
#pragma unroll
  for (int ct = 0; ct < 4; ++ct) {
    f32x4 z = {0.f, 0.f, 0.f, 0.f};
    acc2[ct] = z;
  }
  {
    int lrow = w * 16 + r16;
    short8 b0 = ldH(ht, lrow, kg * 8);
    short8 b1 = ldH(ht, lrow, 32 + kg * 8);
    if (arow < NN) {
      *(short8*)&hout[(size_t)arow * 64 + kg * 8] = b0;
      *(short8*)&hout[(size_t)arow * 64 + 32 + kg * 8] = b1;
    }
#pragma unroll
    for (int ct = 0; ct < 4; ++ct) {
      int c = ct * 16 + r16;
      acc2[ct] = __builtin_amdgcn_mfma_f32_16x16x32_bf16(
          b0, ldW(W1l, 64, c, kg * 8), acc2[ct], 0, 0, 0);
      acc2[ct] = __builtin_amdgcn_mfma_f32_16x16x32_bf16(
          b1, ldW(W1l, 64, c, 32 + kg * 8), acc2[ct], 0, 0, 0);
    }
  }
#pragma unroll
  for (int ct = 0; ct < 4; ++ct) {
    int col = ct * 16 + r16;
#pragma unroll
    for (int i = 0; i < 4; ++i) {
      int row = row_base + kg * 4 + i;
      if (row < NN) H1out[(size_t)row * 64 + col] = f2b(acc2[ct][i]);
    }
  }
}

// fused_final: h5 = relu(h@W2a+hNs@W2b+b2); t = relu(h5@Wl1^T+bl1);
//              out = t@Wl2^T + bl2   (f32)  — 512 threads / 8 waves
__global__ __launch_bounds__(512) void fused_final(
    const unsigned short* __restrict__ h, const unsigned short* __restrict__ hNs,
    const float* __restrict__ W2, const float* __restrict__ b2,
    const float* __restrict__ Wl1, const float* __restrict__ bl1,
    const float* __restrict__ Wl2, const float* __restrict__ bl2,
    float* __restrict__ out) {
  __shared__ unsigned short W2l[64 * 128];
  __shared__ unsigned short Al[64 * 64];
  __shared__ unsigned short Bl[32 * 64];
  __shared__ unsigned short ht[128 * 64];
  int tid = threadIdx.x;
  stageW(W2, 128, W2l, 64, 128, tid, 512);
  stageW(Wl1, 64, Al, 64, 64, tid, 512);
  stageW(Wl2, 64, Bl, 32, 64, tid, 512);
  __syncthreads();
  int w = tid >> 6, l = tid & 63, r16 = l & 15, kg = l >> 4;
  int row_base = blockIdx.x * 128 + w * 16;
  int arow = row_base + r16;
  short8 z8 = {0, 0, 0, 0, 0, 0, 0, 0};
  short8 a0 = z8, a1 = z8, c0 = z8, c1 = z8;
  if (arow < NN) {
    a0 = *(const short8*)&h[(size_t)arow * 64 + kg * 8];
    a1 = *(const short8*)&h[(size_t)arow * 64 + 32 + kg * 8];
    c0 = *(const short8*)&hNs[(size_t)arow * 64 + kg * 8];
    c1 = *(const short8*)&hNs[(size_t)arow * 64 + 32 + kg * 8];
  }
  f32x4 acc[4];
#pragma unroll
  for (int ct = 0; ct < 4; ++ct) {
    f32x4 z = {0.f, 0.f, 0.f, 0.f};
    acc[ct] = z;
  }
#pragma unroll
  for (int ct = 0; ct < 4; ++ct) {
    int c = ct * 16 + r16;
    acc[ct] = __builtin_amdgcn_mfma_f32_16x16x32_bf16(
        a0, ldW(W2l, 128, c, kg * 8), acc[ct], 0, 0, 0);
    acc[ct] = __builtin_amdgcn_mfma_f32_16x16x32_bf16(
        a1, ldW(W2l, 128, c, 32 + kg * 8), acc[ct], 0, 0, 0);
    acc[ct] = __builtin_amdgcn_mfma_f32_16x16x32_bf16(
        c0, ldW(W2l, 128, c, 64 + kg * 8), acc[ct], 0, 0, 0);
    acc[ct] = __builtin_amdgcn_mfma_f32_16x16x32_bf16(
        c1, ldW(W2l, 128, c, 96 + kg * 8), acc[ct], 0, 0, 0);
  }
#pragma unroll
  for (int ct = 0; ct < 4; ++ct) {
    int col = ct * 16 + r16;
    float bv = b2[col];
#pragma unroll
    for (int i = 0; i < 4; ++i) {
      int lrow = w * 16 + kg * 4 + i;
      float v = acc[ct][i] + bv;
      v = fmaxf(v, 0.f);
      stH(ht, lrow, col, f2b(v));
    }
  }
  __syncthreads();
  f32x4 acc2[4];
#pragma unroll
  for (int ct = 0; ct < 4; ++ct) {
    f32x4 z = {0.f, 0.f, 0.f, 0.f};
    acc2[ct] = z;
  }
  {
    int lrow = w * 16 + r16;
    short8 b0 = ldH(ht, lrow, kg * 8);
    short8 b1 = ldH(ht, lrow, 32 + kg * 8);
#pragma unroll
    for (int ct = 0; ct < 4; ++ct) {
      int c = ct * 16 + r16;
      acc2[ct] = __builtin_amdgcn_mfma_f32_16x16x32_bf16(
          b0, ldW(Al, 64, c, kg * 8), acc2[ct], 0, 0, 0);
      acc2[ct] = __builtin_amdgcn_mfma_f32_16x16x32_bf16(
          b1, ldW(Al, 64, c, 32 + kg * 8), acc2[ct], 0, 0, 0);
    }
  }
  __syncthreads();
#pragma unroll
  for (int ct = 0; ct < 4; ++ct) {
    int col = ct * 16 + r16;
    float bv = bl1[col];
#pragma unroll
    for (int i = 0; i < 4; ++i) {
      int lrow = w * 16 + kg * 4 + i;
      float v = acc2[ct][i] + bv;
      v = fmaxf(v, 0.f);
      stH(ht, lrow, col, f2b(v));
    }
  }
  __syncthreads();
  f32x4 acc3[2];
#pragma unroll
  for (int ct = 0; ct < 2; ++ct) {
    f32x4 z = {0.f, 0.f, 0.f, 0.f};
    acc3[ct] = z;
  }
  {
    int lrow = w * 16 + r16;
    short8 b0 = ldH(ht, lrow, kg * 8);
    short8 b1 = ldH(ht, lrow, 32 + kg * 8);
#pragma unroll
    for (int ct = 0; ct < 2; ++ct) {
      int c = ct * 16 + r16;
      acc3[ct] = __builtin_amdgcn_mfma_f32_16x16x32_bf16(
          b0, ldW(Bl, 64, c, kg * 8), acc3[ct], 0, 0, 0);
      acc3[ct] = __builtin_amdgcn_mfma_f32_16x16x32_bf16(
          b1, ldW(Bl, 64, c, 32 + kg * 8), acc3[ct], 0, 0, 0);
    }
  }
#pragma unroll
  for (int ct = 0; ct < 2; ++ct) {
    int col = ct * 16 + r16;
    float bv = bl2[col];
#pragma unroll
    for (int i = 0; i < 4; ++i) {
      int row = row_base + kg * 4 + i;
      if (row < NN) out[(size_t)row * 32 + col] = acc3[ct][i] + bv;
    }
  }
}

// ---------------- launcher ----------------

extern "C" void kernel_launch(void* const* d_in, const int* in_sizes, int n_in,
                              void* d_out, int out_size, void* d_ws, size_t ws_size,
                              hipStream_t stream) {
  const int* gate = (const int*)d_in[0];
  const int* src = (const int*)d_in[1];
  const int* dst = (const int*)d_in[2];
  const float* src_idx = (const float*)d_in[3];
  const float* dst_idx = (const float*)d_in[4];
  const float* rev = (const float*)d_in[5];
  const float* emb = (const float*)d_in[6];
  const float* W1 = (const float*)d_in[7];
  const float* W2 = (const float*)d_in[8];
  const float* b2 = (const float*)d_in[9];
  const float* Wl1 = (const float*)d_in[10];
  const float* bl1 = (const float*)d_in[11];
  const float* Wl2 = (const float*)d_in[12];
  const float* bl2 = (const float*)d_in[13];
  float* out = (float*)d_out;

  char* ws = (char*)d_ws;
  unsigned short* h = (unsigned short*)(ws + 0);             // 12.8 MB
  unsigned short* lbkt = (unsigned short*)(ws + 0);          // aliases h (build)
  unsigned short* H1 = (unsigned short*)(ws + 12800000);     // 12.8 MB
  unsigned short* hNs = (unsigned short*)(ws + 25600000);    // 12.8 MB
  float4* erec_tmp = (float4*)(ws + 25600000);               // aliases hNs (build)
  float4* erec = (float4*)(ws + 38400000);                   // 12.8 MB
  float4* meta = (float4*)(ws + 51200000);                   // 1.6 MB
  int* order = (int*)(ws + 52800000);                        // 0.4 MB
  int* deg = (int*)(ws + 53200000);                          // 0.4 MB
  int* hist_part = (int*)(ws + 53600000);                    // 256*196*4
  int* bucket_start = (int*)(ws + 53810000);                 // 197 ints
  int* nhp = (int*)(ws + 53820000);                          // 196*64*4
  int* nbin_start = (int*)(ws + 53880000);                   // 64 ints

  ehist<<<256, 256, 0, stream>>>(dst, hist_part);
  escan<<<1, 256, 0, stream>>>(hist_part, bucket_start);
  escatter<<<256, 256, 0, stream>>>(dst, src, src_idx, dst_idx, rev, hist_part,
                                    bucket_start, erec_tmp, lbkt);
  bucket_csr<<<NBUCK, 256, 0, stream>>>(lbkt, bucket_start, erec_tmp, erec,
                                        deg, meta, nhp);
  nscan<<<1, 64, 0, stream>>>(nhp, nbin_start);
  nscatter<<<NBUCK, 256, 0, stream>>>(deg, nhp, nbin_start, order);

  fused0<<<782, 256, 0, stream>>>(gate, emb, W1, h, H1);
  for (int i = 0; i < 5; ++i) {
    aggregate<<<6250, 256, 0, stream>>>(H1, meta, order,
                                        erec, W1 + i * 64 * 67, hNs);
    if (i < 4)
      fused_mid<<<782, 512, 0, stream>>>(h, hNs, W2 + i * 64 * 128, b2 + i * 64,
                                         W1 + (i + 1) * 64 * 67, h, H1);
  }
  fused_final<<<782, 512, 0, stream>>>(h, hNs, W2 + 4 * 64 * 128, b2 + 4 * 64,
                                       Wl1, bl1, Wl2, bl2, out);
}